// Round 12
// baseline (201.584 us; speedup 1.0000x reference)
//
#include <hip/hip_runtime.h>

#define N_Q   65536
#define N_C   2048
#define KNN_K 16
#define CDIM  64
#define SLCAP 128
#define KINF  0x7FFFFFFF
#define WSZ   108544  // halves per weight image

#define GN     16     // grid cells per axis
#define GCELLS 4096
#define LCAP   448    // per-cell candidate capacity (u16)
#define LSTORE 512    // padded storage per cell (u16) for safe dwordx4 reads
#define NSLOT  8      // candidate slots per lane (one 16B load)

#define WTBLK  432    // prep blocks doing wtrans work (432*256 = 110,592)

typedef _Float16 half_t;
typedef float v4f __attribute__((ext_vector_type(4)));
typedef half_t v8h __attribute__((ext_vector_type(8)));
typedef unsigned short u16x8 __attribute__((ext_vector_type(8)));

#define ASTRIDE 136   // 128 + 8 pad (halves); row = 272 B = 17*16 B
#define DSTRIDE 40    // 32 + 8 pad

// ---------------------------------------------------------------------------
// DPP lane-xor (wm tree reduction).
// ---------------------------------------------------------------------------
__device__ __forceinline__ int dppx(int v, int j){
  if (j == 1) return __builtin_amdgcn_mov_dpp(v, 0xB1,  0xF, 0xF, true);
  if (j == 2) return __builtin_amdgcn_mov_dpp(v, 0x4E,  0xF, 0xF, true);
  if (j == 8) return __builtin_amdgcn_mov_dpp(v, 0x128, 0xF, 0xF, true);
  return __shfl_xor(v, j, 64);
}
__device__ __forceinline__ float dppxf(float v, int j){
  return __int_as_float(dppx(__float_as_int(v), j));
}

__device__ __forceinline__ int mbcnt64(unsigned long long m){
  return __builtin_amdgcn_mbcnt_hi((unsigned)(m >> 32),
         __builtin_amdgcn_mbcnt_lo((unsigned)m, 0));
}

// Exact 16th-smallest, full-range 31-round bitwise binary search (R9-proven).
__device__ __forceinline__ int select16th(int x){
  int P = 0;
#pragma unroll
  for (int b = 30; b >= 0; --b){
    int cand = P | (1 << b);
    unsigned long long m = __ballot(x < cand);
    if ((int)__popcll(m) < 16) P = cand;
  }
  return P;
}

// Truncated tau search — bits 30..11, fill index bits with 1s (R10-proven).
__device__ __forceinline__ int select16_tau(int x){
  int P = 0;
#pragma unroll
  for (int b = 30; b >= 11; --b){
    int cand = P | (1 << b);
    unsigned long long m = __ballot(x < cand);
    if ((int)__popcll(m) < 16) P = cand;
  }
  return P | 0x7FF;
}

// Rare-path exact 16-NN (full 2048 rescan, register-light).
__device__ __forceinline__ int knn_fallback(const float4* lp, float nqx,
                                            float nqy, float nqz, int lane){
  unsigned used = 0u;
  int keep = KINF;
#pragma unroll 1
  for (int rr = 0; rr < KNN_K; rr++){
    int best = KINF;
#pragma unroll 1
    for (int j = 0; j < 32; j++){
      int c = j*64 + lane;
      float4 P = lp[c];
      float s = fmaf(P.x, nqx, fmaf(P.y, nqy, fmaf(P.z, nqz, P.w)));
      int pv = (__float_as_int(s) & 0xFFFFF800) | c;
      pv = ((used >> j) & 1u) ? KINF : pv;
      best = min(best, pv);
    }
    int gm = best;
#pragma unroll
    for (int off2 = 1; off2 < 64; off2 <<= 1)
      gm = min(gm, __shfl_xor(gm, off2, 64));
    if (lane == rr) keep = gm;
    int gc = gm & 0x7FF;
    if ((gc & 63) == lane) used |= (1u << (gc >> 6));
  }
  return keep;
}

// ---------------------------------------------------------------------------
// Kernel 0 (R12 MERGE): wtrans + grid in one launch. Blocks < WTBLK do the
// weight transpose + cpos4; blocks >= WTBLK build per-cell candidate lists.
// grid part reads cpos DIRECTLY (same float->cell math as via cpos4, bit-
// identical) so there is no intra-kernel dependency. One fewer graph node.
// ---------------------------------------------------------------------------
__global__ __launch_bounds__(256) void prep_kernel(
    const float* W0, const float* W1, const float* W2,
    const float* W3, const float* Wf, const float* Wd,
    const int* indices, const float* cpos,
    half_t* wt, float4* cpos4, unsigned short* list, int* cnt){
  if (blockIdx.x < WTBLK){
    int idx = blockIdx.x * 256 + threadIdx.x;
    if (idx >= WSZ){
      int i = idx - WSZ;
      const float* cp = cpos + (size_t)indices[0] * N_C * 3;
      float x = cp[i*3 + 0], y = cp[i*3 + 1], z = cp[i*3 + 2];
      cpos4[i] = make_float4(x, y, z, fmaf(x, x, fmaf(y, y, fmaf(z, z, 4.0f))));
      return;
    }
    int base, nt, mode;            // mode: 0 plain(src), 1 W0, 2 W2, 3 Wd
    const float* src = W1;
    if (idx < 16384){ base = 0; nt = 8; mode = 1; }
    else if (idx < 32768){ base = 16384; nt = 8; mode = 0; src = W1; }
    else if (idx < 65536){ base = 32768; nt = 8; mode = 2; }
    else if (idx < 81920){ base = 65536; nt = 8; mode = 0; src = W3; }
    else if (idx < 98304){ base = 81920; nt = 8; mode = 0; src = Wf; }
    else { base = 98304; nt = 4; mode = 3; }
    int i = idx - base;
    int tile = i >> 9, e = i & 511;
    int lane = e >> 3, j = e & 7;
    int k0idx = tile / nt, tcol = tile - k0idx*nt;
    int n = tcol*16 + (lane & 15);
    int k = k0idx*32 + ((lane >> 4) << 3) + j;
    float val;
    if (mode == 0)      val = src[k*128 + n];
    else if (mode == 1) val = (k < 127) ? W0[k*128 + n] : 0.f;
    else if (mode == 2) val = (k == 127) ? 0.f
                             : ((k < 127) ? W2[k*128 + n] : W2[(k-1)*128 + n]);
    else                val = (k < 155) ? Wd[k*64 + n] : 0.f;
    wt[idx] = (half_t)val;
  } else {
    // grid part: 4 waves/block, one cell per wave.
    int lane = threadIdx.x & 63, wave = threadIdx.x >> 6;
    int c = (blockIdx.x - WTBLK) * 4 + wave;
    if (c >= GCELLS) return;
    int cx = c & 15, cy = (c >> 4) & 15, cz = c >> 8;
    int lox = min(max(cx - 4, 0), 7);
    int loy = min(max(cy - 4, 0), 7);
    int loz = min(max(cz - 4, 0), 7);
    const float* cp = cpos + (size_t)indices[0] * N_C * 3;
    unsigned short* L = list + (size_t)c * LSTORE;
    int n = 0;
#pragma unroll 1
    for (int b = 0; b < 32; b++){
      int i = b * 64 + lane;
      float x = cp[i*3 + 0], y = cp[i*3 + 1], z = cp[i*3 + 2];
      int ix = min((int)(x * 16.0f), 15);
      int iy = min((int)(y * 16.0f), 15);
      int iz = min((int)(z * 16.0f), 15);
      bool in = ((unsigned)(ix - lox) < 9u) && ((unsigned)(iy - loy) < 9u) &&
                ((unsigned)(iz - loz) < 9u);
      unsigned long long m = __ballot(in);
      if (m){
        int mb = mbcnt64(m);
        if (in && (n + mb) < LCAP) L[n + mb] = (unsigned short)i;
        n += (int)__popcll(m);
      }
    }
    if (lane == 0) cnt[c] = (n <= LCAP) ? n : 0;
  }
}

// ---------------------------------------------------------------------------
// Kernel 1: exact 16-NN + activation staging — R10 version VERBATIM
// (best measured: ~66 us; R11's dual-query regressed and is reverted).
// ---------------------------------------------------------------------------
__global__ __launch_bounds__(512, 6) void knn_kernel(const int* indices,
    const float* qpts, const float4* cpos4, const unsigned short* list,
    const int* cnt, const float* codes, const float* xyzdir,
    half_t* Ain, half_t* Din){
  __shared__ float4 lp[N_C];        // 32 KB
  __shared__ int    sl[8*SLCAP];    // 4 KB
  int tid = threadIdx.x;
  int lane = tid & 63, wave = tid >> 6;
  const float* cc = codes + (size_t)indices[0] * N_C * CDIM;

  for (int c = tid; c < N_C; c += 512) lp[c] = cpos4[c];
  __syncthreads();

  int q = blockIdx.x * 8 + wave;
  float qx = qpts[q*3 + 0];
  float qy = qpts[q*3 + 1];
  float qz = qpts[q*3 + 2];
  float nqx = -2.0f*qx, nqy = -2.0f*qy, nqz = -2.0f*qz;
  float qq = fmaf(qx, qx, fmaf(qy, qy, qz*qz));   // |q|^2

  int cx = min((int)(qx * 16.0f), 15);
  int cy = min((int)(qy * 16.0f), 15);
  int cz = min((int)(qz * 16.0f), 15);
  int cell = cx | (cy << 4) | (cz << 8);
  int lox = min(max(cx - 4, 0), 7);
  int loy = min(max(cy - 4, 0), 7);
  int loz = min(max(cz - 4, 0), 7);
  int nl = cnt[cell];

  // One 16B load: this lane's 8 candidate indices.
  u16x8 cand8 = *(const u16x8*)(list + (size_t)cell * LSTORE + lane * 8);

  int p[NSLOT];
  int lanemin = KINF;
#pragma unroll
  for (int s = 0; s < NSLOT; s++){
    int j = lane*8 + s;
    int idx = (int)cand8[s] & 2047;   // mask stale pad -> safe LDS read
    float4 P = lp[idx];
    float sc = fmaf(P.x, nqx, fmaf(P.y, nqy, fmaf(P.z, nqz, P.w)));
    int pv = (__float_as_int(sc) & 0xFFFFF800) | idx;
    pv = (j < nl) ? pv : KINF;
    asm("" : "+v"(pv));
    p[s] = pv;
    lanemin = min(lanemin, pv);
  }

  // tau: truncated-exact threshold (>= 16 candidates pass, guaranteed).
  int tau = select16_tau(lanemin);

  int* slw = &sl[wave * SLCAP];
  int n = 0;
#pragma unroll
  for (int s = 0; s < NSLOT; s++){
    bool c = (p[s] <= tau);
    unsigned long long m = __ballot(c);
    if (m){
      if (n <= 64){
        if (c){
          int mb = mbcnt64(m);
          slw[n + mb] = p[s];
        }
      }
      n += (int)__popcll(m);
    }
  }
  __builtin_amdgcn_wave_barrier();

  int keep = KINF;
  bool need_fb = true;
  if (n >= KNN_K && n <= 64){
    int x = (lane < n) ? slw[lane] : KINF;
    int P2 = select16th(x);           // exact 16th smallest candidate
    unsigned long long wmask = __ballot(x <= P2);
    int pos = mbcnt64(wmask);
    if (x <= P2) slw[pos] = x;        // exactly 16 winners -> slots 0..15
    __builtin_amdgcn_wave_barrier();
    keep = (lane < KNN_K) ? slw[lane] : KINF;

    // Certificate: d^2 = s - 4 + |q|^2 (truncation < 2^-10) vs clearance^2.
    float d2u = __int_as_float(P2 & 0xFFFFF800) - 4.0f + qq + 0.002f;
    float lofx = lox * 0.0625f, lofy = loy * 0.0625f, lofz = loz * 0.0625f;
    float cl = 1e9f;
    if (lox > 0) cl = fminf(cl, qx - lofx);
    if (lox < 7) cl = fminf(cl, lofx + 0.5625f - qx);
    if (loy > 0) cl = fminf(cl, qy - lofy);
    if (loy < 7) cl = fminf(cl, lofy + 0.5625f - qy);
    if (loz > 0) cl = fminf(cl, qz - lofz);
    if (loz < 7) cl = fminf(cl, lofz + 0.5625f - qz);
    need_fb = !(d2u <= cl * cl);
  }
  if (need_fb) keep = knn_fallback(lp, nqx, nqy, nqz, lane);

  int ci = keep & 0x7FF;
  float4 P = lp[ci];
  float dx = qx - P.x, dy = qy - P.y, dz = qz - P.z;
  float d2 = fmaf(dz, dz, fmaf(dy, dy, dx*dx));
  float w = 1.0f / (d2 + 1e-16f);
  float wm = (lane < KNN_K) ? w : 0.0f;
  wm += dppxf(wm, 1);
  wm += dppxf(wm, 2);
  wm += __shfl_xor(wm, 4, 64);
  wm += dppxf(wm, 8);
  float wn = w / wm;

  // Winner table in LDS (broadcast reads) replaces 32 ds_bpermutes.
  if (lane < KNN_K){
    slw[64 + 2*lane]     = ci;
    slw[64 + 2*lane + 1] = __float_as_int(wn);
  }
  __builtin_amdgcn_wave_barrier();

  float acc = 0.f;
#pragma unroll
  for (int i = 0; i < KNN_K; i++){
    int   cb = slw[64 + 2*i];
    float wb = __int_as_float(slw[64 + 2*i + 1]);
    acc = fmaf(wb, cc[cb*CDIM + lane], acc);
  }
  size_t arow = (size_t)q * ASTRIDE;
  Ain[arow + lane] = (half_t)acc;

  float xv = (lane < 63) ? xyzdir[(size_t)q*90 + lane] : 0.f;
  Ain[arow + 64 + lane] = (half_t)xv;
  if (lane < 8) Ain[arow + 128 + lane] = (half_t)0.f;
  if (lane < 40){
    float dv = (lane < 27) ? xyzdir[(size_t)q*90 + 63 + lane] : 0.f;
    Din[(size_t)q*DSTRIDE + lane] = (half_t)dv;
  }
}

// ---------------------------------------------------------------------------
// Kernel 2: fused MFMA MLP, 64 queries/block — R2 known-good version, frozen.
// ---------------------------------------------------------------------------
template<int NCH, int NT>
__device__ inline void mfma_pl(const half_t* act, int astride, int rowbase,
                               const half_t* wlayer, int nt, int ktbase,
                               int tcolbase, v4f acc[2][NT], int lane){
  v8h breg[NCH*NT];
#pragma unroll
  for (int c = 0; c < NCH; c++){
#pragma unroll
    for (int t = 0; t < NT; t++){
      const half_t* bp = wlayer +
          ((size_t)(((ktbase + c)*nt + tcolbase + t) << 9) + (lane << 3));
      breg[c*NT + t] = *(const v8h*)bp;
    }
  }
  int m = lane & 15, quad = lane >> 4;
#pragma unroll
  for (int c = 0; c < NCH; c++){
    v8h a0 = *(const v8h*)&act[(rowbase + m)*astride + c*32 + quad*8];
    v8h a1 = *(const v8h*)&act[(rowbase + 16 + m)*astride + c*32 + quad*8];
#pragma unroll
    for (int t = 0; t < NT; t++){
      acc[0][t] = __builtin_amdgcn_mfma_f32_16x16x32_f16(a0, breg[c*NT + t], acc[0][t], 0, 0, 0);
      acc[1][t] = __builtin_amdgcn_mfma_f32_16x16x32_f16(a1, breg[c*NT + t], acc[1][t], 0, 0, 0);
    }
  }
}

template<int NT>
__device__ inline void epilogue64(v4f acc[2][NT], half_t* outb, int rowbase,
                                  int colbase, const float* bias, bool relu,
                                  int lane){
  int n = lane & 15, quad = lane >> 4;
#pragma unroll
  for (int t = 0; t < NT; t++){
    int col = colbase + t*16 + n;
    float bv = bias[col];
#pragma unroll
    for (int g = 0; g < 2; g++){
#pragma unroll
      for (int r = 0; r < 4; r++){
        float v = acc[g][t][r] + bv;
        if (relu) v = fmaxf(v, 0.f);
        outb[(rowbase + g*16 + quad*4 + r)*ASTRIDE + col] = (half_t)v;
      }
    }
  }
}

__global__ __launch_bounds__(512, 6) void mlp_mfma(
    const half_t* Ain, const half_t* Din, const half_t* wt,
    const float* b0, const float* b1, const float* b2, const float* b3,
    const float* bfb, const float* bdb,
    const float* Wsb, const float* bsb, const float* Wrb, const float* brb,
    float* out){
  __shared__ __align__(16) half_t Abuf[64*ASTRIDE];
  __shared__ __align__(16) half_t Pbuf[64*ASTRIDE];
  __shared__ __align__(16) half_t Qbuf[64*ASTRIDE];

  int tid = threadIdx.x, lane = tid & 63, wave = tid >> 6;
  int qbase = blockIdx.x * 64;

  for (int i = tid; i < 64*17; i += 512){
    int r = i / 17, c8 = i - r*17;
    *(uint4*)&Abuf[r*ASTRIDE + (c8 << 3)] =
        *(const uint4*)&Ain[(size_t)(qbase + r)*ASTRIDE + (c8 << 3)];
  }
  __syncthreads();

  int rowbase  = (wave >> 2) * 32;
  int colq     = wave & 3;
  int colbase  = colq * 32;
  int tcolbase = colq * 2;
  v4f acc[2][2];
  v4f accd[2][1];

  const half_t* wt0 = wt;
  const half_t* wt1 = wt + 16384;
  const half_t* wt2 = wt + 32768;
  const half_t* wt3 = wt + 65536;
  const half_t* wtf = wt + 81920;
  const half_t* wtd = wt + 98304;

#define ZACC22() { for (int g_ = 0; g_ < 2; g_++) for (int t_ = 0; t_ < 2; t_++) \
                   for (int e_ = 0; e_ < 4; e_++) acc[g_][t_][e_] = 0.f; }

  // L0: A @ W0 -> P (relu)
  ZACC22();
  mfma_pl<4,2>(Abuf, ASTRIDE, rowbase, wt0, 8, 0, tcolbase, acc, lane);
  epilogue64<2>(acc, Pbuf, rowbase, colbase, b0, true, lane);
  __syncthreads();

  // L1: P @ W1 -> Q (relu)
  ZACC22();
  mfma_pl<4,2>(Pbuf, ASTRIDE, rowbase, wt1, 8, 0, tcolbase, acc, lane);
  epilogue64<2>(acc, Qbuf, rowbase, colbase, b1, true, lane);
  __syncthreads();

  // L2: [input_xyz | h1] @ W2 -> P (relu)   (K = 256)
  ZACC22();
  mfma_pl<4,2>(Abuf, ASTRIDE, rowbase, wt2, 8, 0, tcolbase, acc, lane);
  mfma_pl<4,2>(Qbuf, ASTRIDE, rowbase, wt2, 8, 4, tcolbase, acc, lane);
  epilogue64<2>(acc, Pbuf, rowbase, colbase, b2, true, lane);
  __syncthreads();

  // L3: P @ W3 -> A (h3, kept for sigma; input_xyz dead)
  ZACC22();
  mfma_pl<4,2>(Pbuf, ASTRIDE, rowbase, wt3, 8, 0, tcolbase, acc, lane);
  epilogue64<2>(acc, Abuf, rowbase, colbase, b3, true, lane);
  __syncthreads();

  // Wf: A(h3) @ Wf -> P (no relu)
  ZACC22();
  mfma_pl<4,2>(Abuf, ASTRIDE, rowbase, wtf, 8, 0, tcolbase, acc, lane);
  epilogue64<2>(acc, Pbuf, rowbase, colbase, bfb, false, lane);
  __syncthreads();

  // Wd: [P(final) | Din(dir, straight from global/L2)] @ Wd -> Q[:,0:64]
#pragma unroll
  for (int g_ = 0; g_ < 2; g_++)
#pragma unroll
    for (int e_ = 0; e_ < 4; e_++) accd[g_][0][e_] = 0.f;
  mfma_pl<4,1>(Pbuf, ASTRIDE, rowbase, wtd, 4, 0, colq, accd, lane);
  mfma_pl<1,1>(Din + (size_t)qbase*DSTRIDE, DSTRIDE, rowbase, wtd, 4, 4, colq,
               accd, lane);
  epilogue64<1>(accd, Qbuf, rowbase, colq * 16, bdb, true, lane);
  __syncthreads();

  // Tail: sigma = h3(Abuf).Ws + bs ; rgb = d(Qbuf).Wr + br  (8 thr/query)
  {
    int q = tid >> 3, part = tid & 7;
    float s = 0.f;
#pragma unroll
    for (int k = 0; k < 16; k++){
      int kk = part*16 + k;
      s = fmaf((float)Abuf[q*ASTRIDE + kk], Wsb[kk], s);
    }
    s += __shfl_xor(s, 1, 64); s += __shfl_xor(s, 2, 64); s += __shfl_xor(s, 4, 64);

    float r3[3];
#pragma unroll
    for (int c2 = 0; c2 < 3; c2++){
      float rv = 0.f;
#pragma unroll
      for (int k = 0; k < 8; k++){
        int kk = part*8 + k;
        rv = fmaf((float)Qbuf[q*ASTRIDE + kk], Wrb[kk*3 + c2], rv);
      }
      rv += __shfl_xor(rv, 1, 64); rv += __shfl_xor(rv, 2, 64); rv += __shfl_xor(rv, 4, 64);
      r3[c2] = rv;
    }
    if (part == 0){
      size_t ob = ((size_t)(qbase + q)) * 4;
      out[ob + 0] = r3[0] + brb[0];
      out[ob + 1] = r3[1] + brb[1];
      out[ob + 2] = r3[2] + brb[2];
      out[ob + 3] = s + bsb[0];
    }
  }
}

// ---------------------------------------------------------------------------
extern "C" void kernel_launch(void* const* d_in, const int* in_sizes, int n_in,
                              void* d_out, int out_size, void* d_ws, size_t ws_size,
                              hipStream_t stream){
  (void)in_sizes; (void)n_in; (void)out_size; (void)ws_size;

  const int*   indices = (const int*)d_in[0];
  const float* qpts    = (const float*)d_in[1];
  const float* xyzdir  = (const float*)d_in[2];
  const float* cpos    = (const float*)d_in[3];
  const float* codes   = (const float*)d_in[4];
  const float* W0 = (const float*)d_in[5];
  const float* b0 = (const float*)d_in[6];
  const float* W1 = (const float*)d_in[7];
  const float* b1 = (const float*)d_in[8];
  const float* W2 = (const float*)d_in[9];
  const float* b2 = (const float*)d_in[10];
  const float* W3 = (const float*)d_in[11];
  const float* b3 = (const float*)d_in[12];
  const float* Wf = (const float*)d_in[13];
  const float* bf = (const float*)d_in[14];
  const float* Wd = (const float*)d_in[15];
  const float* bd = (const float*)d_in[16];
  const float* Ws = (const float*)d_in[17];
  const float* bs = (const float*)d_in[18];
  const float* Wr = (const float*)d_in[19];
  const float* br = (const float*)d_in[20];

  // ws layout (16-B aligned): Ain | Din | wt | cpos4 | list | cnt
  half_t* Ain            = (half_t*)d_ws;                          // 17,825,792
  half_t* Din            = (half_t*)((char*)d_ws + 17825792);      //  5,242,880
  half_t* wt             = (half_t*)((char*)d_ws + 23068672);      //    217,088
  float4* cpos4          = (float4*)((char*)d_ws + 23285760);      //     32,768
  unsigned short* list   = (unsigned short*)((char*)d_ws + 23318528); // 4,194,304
  int* cnt               = (int*)((char*)d_ws + 27512832);         //     16,384

  // prep: wtrans blocks [0, 432) + grid blocks [432, 432+1024)
  prep_kernel<<<WTBLK + GCELLS/4, 256, 0, stream>>>(W0, W1, W2, W3, Wf, Wd,
                                                    indices, cpos, wt, cpos4,
                                                    list, cnt);
  knn_kernel<<<N_Q/8, 512, 0, stream>>>(indices, qpts, cpos4, list, cnt,
                                        codes, xyzdir, Ain, Din);
  mlp_mfma<<<N_Q/64, 512, 0, stream>>>(Ain, Din, wt,
                                       b0, b1, b2, b3, bf, bd, Ws, bs, Wr, br,
                                       (float*)d_out);
}

// Round 13
// 198.710 us; speedup vs baseline: 1.0145x; 1.0145x over previous
//
#include <hip/hip_runtime.h>

#define N_Q   65536
#define N_C   2048
#define KNN_K 16
#define CDIM  64
#define SLCAP 128
#define KINF  0x7FFFFFFF
#define WSZ   108544  // halves per weight image

#define GN     16     // grid cells per axis
#define GCELLS 4096
#define LCAP   448    // per-cell candidate capacity (u16)
#define LSTORE 512    // padded storage per cell (u16) for safe dwordx4 reads
#define NSLOT  8      // candidate slots per lane (one 16B load)

#define WTBLK2 216    // wtrans blocks folded into knn launch (216*512 >= WSZ)
#define KNNBLK 8192   // knn query blocks

typedef _Float16 half_t;
typedef float v4f __attribute__((ext_vector_type(4)));
typedef half_t v8h __attribute__((ext_vector_type(8)));
typedef unsigned short u16x8 __attribute__((ext_vector_type(8)));

#define ASTRIDE 136   // 128 + 8 pad (halves); row = 272 B = 17*16 B
#define DSTRIDE 40    // 32 + 8 pad

// ---------------------------------------------------------------------------
// DPP lane-xor (wm tree reduction).
// ---------------------------------------------------------------------------
__device__ __forceinline__ int dppx(int v, int j){
  if (j == 1) return __builtin_amdgcn_mov_dpp(v, 0xB1,  0xF, 0xF, true);
  if (j == 2) return __builtin_amdgcn_mov_dpp(v, 0x4E,  0xF, 0xF, true);
  if (j == 8) return __builtin_amdgcn_mov_dpp(v, 0x128, 0xF, 0xF, true);
  return __shfl_xor(v, j, 64);
}
__device__ __forceinline__ float dppxf(float v, int j){
  return __int_as_float(dppx(__float_as_int(v), j));
}

__device__ __forceinline__ int mbcnt64(unsigned long long m){
  return __builtin_amdgcn_mbcnt_hi((unsigned)(m >> 32),
         __builtin_amdgcn_mbcnt_lo((unsigned)m, 0));
}

// R13: packed scores s = d^2+4-|q|^2 lie in (1,8) -> values in
// [0x3F800000, 0x41000000). Additive binary search from base B finds the
// SAME maximal P (count(x<P) < 16) as the full OR-search — bit-exact —
// in 25 rounds instead of 31 (winner) / 14 instead of 20 (tau).
// KINF padding >= any candidate, never counted.
__device__ __forceinline__ int select16th(int x){
  int P = 0x3F800000;
#pragma unroll
  for (int b = 24; b >= 0; --b){
    int cand = P + (1 << b);
    unsigned long long m = __ballot(x < cand);
    if ((int)__popcll(m) < 16) P = cand;
  }
  return P;
}

// Truncated tau: bits 24..11 additively, then fill index bits (low 11 of
// base are 0, so P|0x7FF = P+0x7FF; count(x <= tau) >= 16 still guaranteed).
__device__ __forceinline__ int select16_tau(int x){
  int P = 0x3F800000;
#pragma unroll
  for (int b = 24; b >= 11; --b){
    int cand = P + (1 << b);
    unsigned long long m = __ballot(x < cand);
    if ((int)__popcll(m) < 16) P = cand;
  }
  return P | 0x7FF;
}

// Rare-path exact 16-NN (full 2048 rescan, register-light).
__device__ __forceinline__ int knn_fallback(const float4* lp, float nqx,
                                            float nqy, float nqz, int lane){
  unsigned used = 0u;
  int keep = KINF;
#pragma unroll 1
  for (int rr = 0; rr < KNN_K; rr++){
    int best = KINF;
#pragma unroll 1
    for (int j = 0; j < 32; j++){
      int c = j*64 + lane;
      float4 P = lp[c];
      float s = fmaf(P.x, nqx, fmaf(P.y, nqy, fmaf(P.z, nqz, P.w)));
      int pv = (__float_as_int(s) & 0xFFFFF800) | c;
      pv = ((used >> j) & 1u) ? KINF : pv;
      best = min(best, pv);
    }
    int gm = best;
#pragma unroll
    for (int off2 = 1; off2 < 64; off2 <<= 1)
      gm = min(gm, __shfl_xor(gm, off2, 64));
    if (lane == rr) keep = gm;
    int gc = gm & 0x7FF;
    if ((gc & 63) == lane) used |= (1u << (gc >> 6));
  }
  return keep;
}

// ---------------------------------------------------------------------------
// Kernel 0 (R13): prep = grid candidate lists + cpos4 ONLY (small, ~3 us).
// The weight transpose moved into the knn launch (it feeds only mlp, so it
// can overlap knn; launch boundary guarantees wt is ready for mlp).
// cpos4 stays here because knn blocks read it at kernel start.
// ---------------------------------------------------------------------------
__global__ __launch_bounds__(512) void prep_kernel(
    const int* indices, const float* cpos,
    float4* cpos4, unsigned short* list, int* cnt){
  const float* cp = cpos + (size_t)indices[0] * N_C * 3;
  if (blockIdx.x >= GCELLS/8){
    // cpos4 part: blocks [128, 132)
    int i = (blockIdx.x - GCELLS/8) * 512 + threadIdx.x;
    if (i < N_C){
      float x = cp[i*3 + 0], y = cp[i*3 + 1], z = cp[i*3 + 2];
      cpos4[i] = make_float4(x, y, z, fmaf(x, x, fmaf(y, y, fmaf(z, z, 4.0f))));
    }
    return;
  }
  // grid part: 8 waves/block, one cell per wave.
  int lane = threadIdx.x & 63, wave = threadIdx.x >> 6;
  int c = blockIdx.x * 8 + wave;
  int cx = c & 15, cy = (c >> 4) & 15, cz = c >> 8;
  int lox = min(max(cx - 4, 0), 7);
  int loy = min(max(cy - 4, 0), 7);
  int loz = min(max(cz - 4, 0), 7);
  unsigned short* L = list + (size_t)c * LSTORE;
  int n = 0;
#pragma unroll 1
  for (int b = 0; b < 32; b++){
    int i = b * 64 + lane;
    float x = cp[i*3 + 0], y = cp[i*3 + 1], z = cp[i*3 + 2];
    int ix = min((int)(x * 16.0f), 15);
    int iy = min((int)(y * 16.0f), 15);
    int iz = min((int)(z * 16.0f), 15);
    bool in = ((unsigned)(ix - lox) < 9u) && ((unsigned)(iy - loy) < 9u) &&
              ((unsigned)(iz - loz) < 9u);
    unsigned long long m = __ballot(in);
    if (m){
      int mb = mbcnt64(m);
      if (in && (n + mb) < LCAP) L[n + mb] = (unsigned short)i;
      n += (int)__popcll(m);
    }
  }
  if (lane == 0) cnt[c] = (n <= LCAP) ? n : 0;
}

// ---------------------------------------------------------------------------
// Kernel 1 (R13): knn launch = 216 wtrans blocks (low blockIdx, dispatch
// early, memory-bound -> overlap with VALU-bound knn blocks) + 8192 knn
// query blocks (R10-proven algorithm, trimmed selects).
// ---------------------------------------------------------------------------
__global__ __launch_bounds__(512, 6) void knn_kernel(const int* indices,
    const float* qpts, const float4* cpos4, const unsigned short* list,
    const int* cnt, const float* codes, const float* xyzdir,
    const float* W0, const float* W1, const float* W2, const float* W3,
    const float* Wf, const float* Wd, half_t* wt,
    half_t* Ain, half_t* Din){
  if (blockIdx.x < WTBLK2){
    // ---- weight transpose (feeds mlp only; no knn block reads wt) ----
    int idx = blockIdx.x * 512 + threadIdx.x;
    if (idx >= WSZ) return;
    int base, nt, mode;            // mode: 0 plain(src), 1 W0, 2 W2, 3 Wd
    const float* src = W1;
    if (idx < 16384){ base = 0; nt = 8; mode = 1; }
    else if (idx < 32768){ base = 16384; nt = 8; mode = 0; src = W1; }
    else if (idx < 65536){ base = 32768; nt = 8; mode = 2; }
    else if (idx < 81920){ base = 65536; nt = 8; mode = 0; src = W3; }
    else if (idx < 98304){ base = 81920; nt = 8; mode = 0; src = Wf; }
    else { base = 98304; nt = 4; mode = 3; }
    int i = idx - base;
    int tile = i >> 9, e = i & 511;
    int lane = e >> 3, j = e & 7;
    int k0idx = tile / nt, tcol = tile - k0idx*nt;
    int n = tcol*16 + (lane & 15);
    int k = k0idx*32 + ((lane >> 4) << 3) + j;
    float val;
    if (mode == 0)      val = src[k*128 + n];
    else if (mode == 1) val = (k < 127) ? W0[k*128 + n] : 0.f;
    else if (mode == 2) val = (k == 127) ? 0.f
                             : ((k < 127) ? W2[k*128 + n] : W2[(k-1)*128 + n]);
    else                val = (k < 155) ? Wd[k*64 + n] : 0.f;
    wt[idx] = (half_t)val;
    return;
  }

  __shared__ float4 lp[N_C];        // 32 KB
  __shared__ int    sl[8*SLCAP];    // 4 KB
  int tid = threadIdx.x;
  int lane = tid & 63, wave = tid >> 6;
  const float* cc = codes + (size_t)indices[0] * N_C * CDIM;

  for (int c = tid; c < N_C; c += 512) lp[c] = cpos4[c];
  __syncthreads();

  int q = (blockIdx.x - WTBLK2) * 8 + wave;
  float qx = qpts[q*3 + 0];
  float qy = qpts[q*3 + 1];
  float qz = qpts[q*3 + 2];
  float nqx = -2.0f*qx, nqy = -2.0f*qy, nqz = -2.0f*qz;
  float qq = fmaf(qx, qx, fmaf(qy, qy, qz*qz));   // |q|^2

  int cx = min((int)(qx * 16.0f), 15);
  int cy = min((int)(qy * 16.0f), 15);
  int cz = min((int)(qz * 16.0f), 15);
  int cell = cx | (cy << 4) | (cz << 8);
  int lox = min(max(cx - 4, 0), 7);
  int loy = min(max(cy - 4, 0), 7);
  int loz = min(max(cz - 4, 0), 7);
  int nl = cnt[cell];

  // One 16B load: this lane's 8 candidate indices.
  u16x8 cand8 = *(const u16x8*)(list + (size_t)cell * LSTORE + lane * 8);

  int p[NSLOT];
  int lanemin = KINF;
#pragma unroll
  for (int s = 0; s < NSLOT; s++){
    int j = lane*8 + s;
    int idx = (int)cand8[s] & 2047;   // mask stale pad -> safe LDS read
    float4 P = lp[idx];
    float sc = fmaf(P.x, nqx, fmaf(P.y, nqy, fmaf(P.z, nqz, P.w)));
    int pv = (__float_as_int(sc) & 0xFFFFF800) | idx;
    pv = (j < nl) ? pv : KINF;
    asm("" : "+v"(pv));
    p[s] = pv;
    lanemin = min(lanemin, pv);
  }

  // tau: truncated-exact threshold (>= 16 candidates pass, guaranteed).
  int tau = select16_tau(lanemin);

  int* slw = &sl[wave * SLCAP];
  int n = 0;
#pragma unroll
  for (int s = 0; s < NSLOT; s++){
    bool c = (p[s] <= tau);
    unsigned long long m = __ballot(c);
    if (m){
      if (n <= 64){
        if (c){
          int mb = mbcnt64(m);
          slw[n + mb] = p[s];
        }
      }
      n += (int)__popcll(m);
    }
  }
  __builtin_amdgcn_wave_barrier();

  int keep = KINF;
  bool need_fb = true;
  if (n >= KNN_K && n <= 64){
    int x = (lane < n) ? slw[lane] : KINF;
    int P2 = select16th(x);           // exact 16th smallest candidate
    unsigned long long wmask = __ballot(x <= P2);
    int pos = mbcnt64(wmask);
    if (x <= P2) slw[pos] = x;        // exactly 16 winners -> slots 0..15
    __builtin_amdgcn_wave_barrier();
    keep = (lane < KNN_K) ? slw[lane] : KINF;

    // Certificate: d^2 = s - 4 + |q|^2 (truncation < 2^-10) vs clearance^2.
    float d2u = __int_as_float(P2 & 0xFFFFF800) - 4.0f + qq + 0.002f;
    float lofx = lox * 0.0625f, lofy = loy * 0.0625f, lofz = loz * 0.0625f;
    float cl = 1e9f;
    if (lox > 0) cl = fminf(cl, qx - lofx);
    if (lox < 7) cl = fminf(cl, lofx + 0.5625f - qx);
    if (loy > 0) cl = fminf(cl, qy - lofy);
    if (loy < 7) cl = fminf(cl, lofy + 0.5625f - qy);
    if (loz > 0) cl = fminf(cl, qz - lofz);
    if (loz < 7) cl = fminf(cl, lofz + 0.5625f - qz);
    need_fb = !(d2u <= cl * cl);
  }
  if (need_fb) keep = knn_fallback(lp, nqx, nqy, nqz, lane);

  int ci = keep & 0x7FF;
  float4 P = lp[ci];
  float dx = qx - P.x, dy = qy - P.y, dz = qz - P.z;
  float d2 = fmaf(dz, dz, fmaf(dy, dy, dx*dx));
  float w = 1.0f / (d2 + 1e-16f);
  float wm = (lane < KNN_K) ? w : 0.0f;
  wm += dppxf(wm, 1);
  wm += dppxf(wm, 2);
  wm += __shfl_xor(wm, 4, 64);
  wm += dppxf(wm, 8);
  float wn = w / wm;

  // Winner table in LDS (broadcast reads) replaces 32 ds_bpermutes.
  if (lane < KNN_K){
    slw[64 + 2*lane]     = ci;
    slw[64 + 2*lane + 1] = __float_as_int(wn);
  }
  __builtin_amdgcn_wave_barrier();

  float acc = 0.f;
#pragma unroll
  for (int i = 0; i < KNN_K; i++){
    int   cb = slw[64 + 2*i];
    float wb = __int_as_float(slw[64 + 2*i + 1]);
    acc = fmaf(wb, cc[cb*CDIM + lane], acc);
  }
  size_t arow = (size_t)q * ASTRIDE;
  Ain[arow + lane] = (half_t)acc;

  float xv = (lane < 63) ? xyzdir[(size_t)q*90 + lane] : 0.f;
  Ain[arow + 64 + lane] = (half_t)xv;
  if (lane < 8) Ain[arow + 128 + lane] = (half_t)0.f;
  if (lane < 40){
    float dv = (lane < 27) ? xyzdir[(size_t)q*90 + 63 + lane] : 0.f;
    Din[(size_t)q*DSTRIDE + lane] = (half_t)dv;
  }
}

// ---------------------------------------------------------------------------
// Kernel 2: fused MFMA MLP, 64 queries/block — R2 known-good version, frozen.
// ---------------------------------------------------------------------------
template<int NCH, int NT>
__device__ inline void mfma_pl(const half_t* act, int astride, int rowbase,
                               const half_t* wlayer, int nt, int ktbase,
                               int tcolbase, v4f acc[2][NT], int lane){
  v8h breg[NCH*NT];
#pragma unroll
  for (int c = 0; c < NCH; c++){
#pragma unroll
    for (int t = 0; t < NT; t++){
      const half_t* bp = wlayer +
          ((size_t)(((ktbase + c)*nt + tcolbase + t) << 9) + (lane << 3));
      breg[c*NT + t] = *(const v8h*)bp;
    }
  }
  int m = lane & 15, quad = lane >> 4;
#pragma unroll
  for (int c = 0; c < NCH; c++){
    v8h a0 = *(const v8h*)&act[(rowbase + m)*astride + c*32 + quad*8];
    v8h a1 = *(const v8h*)&act[(rowbase + 16 + m)*astride + c*32 + quad*8];
#pragma unroll
    for (int t = 0; t < NT; t++){
      acc[0][t] = __builtin_amdgcn_mfma_f32_16x16x32_f16(a0, breg[c*NT + t], acc[0][t], 0, 0, 0);
      acc[1][t] = __builtin_amdgcn_mfma_f32_16x16x32_f16(a1, breg[c*NT + t], acc[1][t], 0, 0, 0);
    }
  }
}

template<int NT>
__device__ inline void epilogue64(v4f acc[2][NT], half_t* outb, int rowbase,
                                  int colbase, const float* bias, bool relu,
                                  int lane){
  int n = lane & 15, quad = lane >> 4;
#pragma unroll
  for (int t = 0; t < NT; t++){
    int col = colbase + t*16 + n;
    float bv = bias[col];
#pragma unroll
    for (int g = 0; g < 2; g++){
#pragma unroll
      for (int r = 0; r < 4; r++){
        float v = acc[g][t][r] + bv;
        if (relu) v = fmaxf(v, 0.f);
        outb[(rowbase + g*16 + quad*4 + r)*ASTRIDE + col] = (half_t)v;
      }
    }
  }
}

__global__ __launch_bounds__(512, 6) void mlp_mfma(
    const half_t* Ain, const half_t* Din, const half_t* wt,
    const float* b0, const float* b1, const float* b2, const float* b3,
    const float* bfb, const float* bdb,
    const float* Wsb, const float* bsb, const float* Wrb, const float* brb,
    float* out){
  __shared__ __align__(16) half_t Abuf[64*ASTRIDE];
  __shared__ __align__(16) half_t Pbuf[64*ASTRIDE];
  __shared__ __align__(16) half_t Qbuf[64*ASTRIDE];

  int tid = threadIdx.x, lane = tid & 63, wave = tid >> 6;
  int qbase = blockIdx.x * 64;

  for (int i = tid; i < 64*17; i += 512){
    int r = i / 17, c8 = i - r*17;
    *(uint4*)&Abuf[r*ASTRIDE + (c8 << 3)] =
        *(const uint4*)&Ain[(size_t)(qbase + r)*ASTRIDE + (c8 << 3)];
  }
  __syncthreads();

  int rowbase  = (wave >> 2) * 32;
  int colq     = wave & 3;
  int colbase  = colq * 32;
  int tcolbase = colq * 2;
  v4f acc[2][2];
  v4f accd[2][1];

  const half_t* wt0 = wt;
  const half_t* wt1 = wt + 16384;
  const half_t* wt2 = wt + 32768;
  const half_t* wt3 = wt + 65536;
  const half_t* wtf = wt + 81920;
  const half_t* wtd = wt + 98304;

#define ZACC22() { for (int g_ = 0; g_ < 2; g_++) for (int t_ = 0; t_ < 2; t_++) \
                   for (int e_ = 0; e_ < 4; e_++) acc[g_][t_][e_] = 0.f; }

  // L0: A @ W0 -> P (relu)
  ZACC22();
  mfma_pl<4,2>(Abuf, ASTRIDE, rowbase, wt0, 8, 0, tcolbase, acc, lane);
  epilogue64<2>(acc, Pbuf, rowbase, colbase, b0, true, lane);
  __syncthreads();

  // L1: P @ W1 -> Q (relu)
  ZACC22();
  mfma_pl<4,2>(Pbuf, ASTRIDE, rowbase, wt1, 8, 0, tcolbase, acc, lane);
  epilogue64<2>(acc, Qbuf, rowbase, colbase, b1, true, lane);
  __syncthreads();

  // L2: [input_xyz | h1] @ W2 -> P (relu)   (K = 256)
  ZACC22();
  mfma_pl<4,2>(Abuf, ASTRIDE, rowbase, wt2, 8, 0, tcolbase, acc, lane);
  mfma_pl<4,2>(Qbuf, ASTRIDE, rowbase, wt2, 8, 4, tcolbase, acc, lane);
  epilogue64<2>(acc, Pbuf, rowbase, colbase, b2, true, lane);
  __syncthreads();

  // L3: P @ W3 -> A (h3, kept for sigma; input_xyz dead)
  ZACC22();
  mfma_pl<4,2>(Pbuf, ASTRIDE, rowbase, wt3, 8, 0, tcolbase, acc, lane);
  epilogue64<2>(acc, Abuf, rowbase, colbase, b3, true, lane);
  __syncthreads();

  // Wf: A(h3) @ Wf -> P (no relu)
  ZACC22();
  mfma_pl<4,2>(Abuf, ASTRIDE, rowbase, wtf, 8, 0, tcolbase, acc, lane);
  epilogue64<2>(acc, Pbuf, rowbase, colbase, bfb, false, lane);
  __syncthreads();

  // Wd: [P(final) | Din(dir, straight from global/L2)] @ Wd -> Q[:,0:64]
#pragma unroll
  for (int g_ = 0; g_ < 2; g_++)
#pragma unroll
    for (int e_ = 0; e_ < 4; e_++) accd[g_][0][e_] = 0.f;
  mfma_pl<4,1>(Pbuf, ASTRIDE, rowbase, wtd, 4, 0, colq, accd, lane);
  mfma_pl<1,1>(Din + (size_t)qbase*DSTRIDE, DSTRIDE, rowbase, wtd, 4, 4, colq,
               accd, lane);
  epilogue64<1>(accd, Qbuf, rowbase, colq * 16, bdb, true, lane);
  __syncthreads();

  // Tail: sigma = h3(Abuf).Ws + bs ; rgb = d(Qbuf).Wr + br  (8 thr/query)
  {
    int q = tid >> 3, part = tid & 7;
    float s = 0.f;
#pragma unroll
    for (int k = 0; k < 16; k++){
      int kk = part*16 + k;
      s = fmaf((float)Abuf[q*ASTRIDE + kk], Wsb[kk], s);
    }
    s += __shfl_xor(s, 1, 64); s += __shfl_xor(s, 2, 64); s += __shfl_xor(s, 4, 64);

    float r3[3];
#pragma unroll
    for (int c2 = 0; c2 < 3; c2++){
      float rv = 0.f;
#pragma unroll
      for (int k = 0; k < 8; k++){
        int kk = part*8 + k;
        rv = fmaf((float)Qbuf[q*ASTRIDE + kk], Wrb[kk*3 + c2], rv);
      }
      rv += __shfl_xor(rv, 1, 64); rv += __shfl_xor(rv, 2, 64); rv += __shfl_xor(rv, 4, 64);
      r3[c2] = rv;
    }
    if (part == 0){
      size_t ob = ((size_t)(qbase + q)) * 4;
      out[ob + 0] = r3[0] + brb[0];
      out[ob + 1] = r3[1] + brb[1];
      out[ob + 2] = r3[2] + brb[2];
      out[ob + 3] = s + bsb[0];
    }
  }
}

// ---------------------------------------------------------------------------
extern "C" void kernel_launch(void* const* d_in, const int* in_sizes, int n_in,
                              void* d_out, int out_size, void* d_ws, size_t ws_size,
                              hipStream_t stream){
  (void)in_sizes; (void)n_in; (void)out_size; (void)ws_size;

  const int*   indices = (const int*)d_in[0];
  const float* qpts    = (const float*)d_in[1];
  const float* xyzdir  = (const float*)d_in[2];
  const float* cpos    = (const float*)d_in[3];
  const float* codes   = (const float*)d_in[4];
  const float* W0 = (const float*)d_in[5];
  const float* b0 = (const float*)d_in[6];
  const float* W1 = (const float*)d_in[7];
  const float* b1 = (const float*)d_in[8];
  const float* W2 = (const float*)d_in[9];
  const float* b2 = (const float*)d_in[10];
  const float* W3 = (const float*)d_in[11];
  const float* b3 = (const float*)d_in[12];
  const float* Wf = (const float*)d_in[13];
  const float* bf = (const float*)d_in[14];
  const float* Wd = (const float*)d_in[15];
  const float* bd = (const float*)d_in[16];
  const float* Ws = (const float*)d_in[17];
  const float* bs = (const float*)d_in[18];
  const float* Wr = (const float*)d_in[19];
  const float* br = (const float*)d_in[20];

  // ws layout (16-B aligned): Ain | Din | wt | cpos4 | list | cnt
  half_t* Ain            = (half_t*)d_ws;                          // 17,825,792
  half_t* Din            = (half_t*)((char*)d_ws + 17825792);      //  5,242,880
  half_t* wt             = (half_t*)((char*)d_ws + 23068672);      //    217,088
  float4* cpos4          = (float4*)((char*)d_ws + 23285760);      //     32,768
  unsigned short* list   = (unsigned short*)((char*)d_ws + 23318528); // 4,194,304
  int* cnt               = (int*)((char*)d_ws + 27512832);         //     16,384

  // prep: grid lists (128 blocks) + cpos4 (4 blocks)
  prep_kernel<<<GCELLS/8 + 4, 512, 0, stream>>>(indices, cpos,
                                                cpos4, list, cnt);
  // knn launch: 216 wtrans blocks (overlap) + 8192 query blocks
  knn_kernel<<<WTBLK2 + KNNBLK, 512, 0, stream>>>(indices, qpts, cpos4, list,
                                                  cnt, codes, xyzdir,
                                                  W0, W1, W2, W3, Wf, Wd, wt,
                                                  Ain, Din);
  mlp_mfma<<<N_Q/64, 512, 0, stream>>>(Ain, Din, wt,
                                       b0, b1, b2, b3, bf, bd, Ws, bs, Wr, br,
                                       (float*)d_out);
}

// Round 14
// 196.758 us; speedup vs baseline: 1.0245x; 1.0099x over previous
//
#include <hip/hip_runtime.h>

#define N_Q   65536
#define N_C   2048
#define KNN_K 16
#define CDIM  64
#define SLCAP 128
#define KINF  0x7FFFFFFF
#define WSZ   108544  // halves per weight image

#define GN     16     // grid cells per axis
#define GCELLS 4096
#define LCAP   448    // per-cell candidate capacity (u16)
#define LSTORE 512    // padded storage per cell (u16) for safe dwordx4 reads
#define NSLOT  8      // candidate slots per lane (one 16B load)

#define WTBLK2 106    // wtrans blocks folded into knn launch (106*1024 = WSZ)
#define KNNBLK 4096   // knn query blocks (16 queries each)

typedef _Float16 half_t;
typedef float v4f __attribute__((ext_vector_type(4)));
typedef half_t v8h __attribute__((ext_vector_type(8)));
typedef unsigned short u16x8 __attribute__((ext_vector_type(8)));

#define ASTRIDE 136   // 128 + 8 pad (halves); row = 272 B = 17*16 B
#define DSTRIDE 40    // 32 + 8 pad

// ---------------------------------------------------------------------------
// DPP lane-xor (wm tree reduction).
// ---------------------------------------------------------------------------
__device__ __forceinline__ int dppx(int v, int j){
  if (j == 1) return __builtin_amdgcn_mov_dpp(v, 0xB1,  0xF, 0xF, true);
  if (j == 2) return __builtin_amdgcn_mov_dpp(v, 0x4E,  0xF, 0xF, true);
  if (j == 8) return __builtin_amdgcn_mov_dpp(v, 0x128, 0xF, 0xF, true);
  return __shfl_xor(v, j, 64);
}
__device__ __forceinline__ float dppxf(float v, int j){
  return __int_as_float(dppx(__float_as_int(v), j));
}

__device__ __forceinline__ int mbcnt64(unsigned long long m){
  return __builtin_amdgcn_mbcnt_hi((unsigned)(m >> 32),
         __builtin_amdgcn_mbcnt_lo((unsigned)m, 0));
}

// Packed scores s = d^2+4-|q|^2 lie in (1,8) -> values in
// [0x3F800000, 0x41000000). Additive binary search from base (bit-exact
// vs full OR-search): 25 rounds (winner) / 14 rounds (tau).
__device__ __forceinline__ int select16th(int x){
  int P = 0x3F800000;
#pragma unroll
  for (int b = 24; b >= 0; --b){
    int cand = P + (1 << b);
    unsigned long long m = __ballot(x < cand);
    if ((int)__popcll(m) < 16) P = cand;
  }
  return P;
}

__device__ __forceinline__ int select16_tau(int x){
  int P = 0x3F800000;
#pragma unroll
  for (int b = 24; b >= 11; --b){
    int cand = P + (1 << b);
    unsigned long long m = __ballot(x < cand);
    if ((int)__popcll(m) < 16) P = cand;
  }
  return P | 0x7FF;
}

// Rare-path exact 16-NN (full 2048 rescan, register-light).
__device__ __forceinline__ int knn_fallback(const float4* lp, float nqx,
                                            float nqy, float nqz, int lane){
  unsigned used = 0u;
  int keep = KINF;
#pragma unroll 1
  for (int rr = 0; rr < KNN_K; rr++){
    int best = KINF;
#pragma unroll 1
    for (int j = 0; j < 32; j++){
      int c = j*64 + lane;
      float4 P = lp[c];
      float s = fmaf(P.x, nqx, fmaf(P.y, nqy, fmaf(P.z, nqz, P.w)));
      int pv = (__float_as_int(s) & 0xFFFFF800) | c;
      pv = ((used >> j) & 1u) ? KINF : pv;
      best = min(best, pv);
    }
    int gm = best;
#pragma unroll
    for (int off2 = 1; off2 < 64; off2 <<= 1)
      gm = min(gm, __shfl_xor(gm, off2, 64));
    if (lane == rr) keep = gm;
    int gc = gm & 0x7FF;
    if ((gc & 63) == lane) used |= (1u << (gc >> 6));
  }
  return keep;
}

// ---------------------------------------------------------------------------
// Kernel 0: prep = grid candidate lists + cpos4 (small, ~3 us).
// ---------------------------------------------------------------------------
__global__ __launch_bounds__(512) void prep_kernel(
    const int* indices, const float* cpos,
    float4* cpos4, unsigned short* list, int* cnt){
  const float* cp = cpos + (size_t)indices[0] * N_C * 3;
  if (blockIdx.x >= GCELLS/8){
    // cpos4 part: blocks [128, 132)
    int i = (blockIdx.x - GCELLS/8) * 512 + threadIdx.x;
    if (i < N_C){
      float x = cp[i*3 + 0], y = cp[i*3 + 1], z = cp[i*3 + 2];
      cpos4[i] = make_float4(x, y, z, fmaf(x, x, fmaf(y, y, fmaf(z, z, 4.0f))));
    }
    return;
  }
  // grid part: 8 waves/block, one cell per wave.
  int lane = threadIdx.x & 63, wave = threadIdx.x >> 6;
  int c = blockIdx.x * 8 + wave;
  int cx = c & 15, cy = (c >> 4) & 15, cz = c >> 8;
  int lox = min(max(cx - 4, 0), 7);
  int loy = min(max(cy - 4, 0), 7);
  int loz = min(max(cz - 4, 0), 7);
  unsigned short* L = list + (size_t)c * LSTORE;
  int n = 0;
#pragma unroll 1
  for (int b = 0; b < 32; b++){
    int i = b * 64 + lane;
    float x = cp[i*3 + 0], y = cp[i*3 + 1], z = cp[i*3 + 2];
    int ix = min((int)(x * 16.0f), 15);
    int iy = min((int)(y * 16.0f), 15);
    int iz = min((int)(z * 16.0f), 15);
    bool in = ((unsigned)(ix - lox) < 9u) && ((unsigned)(iy - loy) < 9u) &&
              ((unsigned)(iz - loz) < 9u);
    unsigned long long m = __ballot(in);
    if (m){
      int mb = mbcnt64(m);
      if (in && (n + mb) < LCAP) L[n + mb] = (unsigned short)i;
      n += (int)__popcll(m);
    }
  }
  if (lane == 0) cnt[c] = (n <= LCAP) ? n : 0;
}

// ---------------------------------------------------------------------------
// Kernel 1 (R14): 1024-thread knn blocks — 16 queries/block, 16 waves.
// 2 blocks/CU x 16 waves = 32 waves/CU (100% occupancy) vs the 3-block
// quantization cap (24 waves, 75%) that 512-thread blocks were stuck at
// (R5 proved launch_bounds wasn't the cap; LDS granule rounding was).
// lp staging amortizes over 16 queries. Per-query math bit-identical.
// + 106 wtrans blocks folded in (overlap; feeds mlp only).
// ---------------------------------------------------------------------------
__global__ __launch_bounds__(1024, 8) void knn_kernel(const int* indices,
    const float* qpts, const float4* cpos4, const unsigned short* list,
    const int* cnt, const float* codes, const float* xyzdir,
    const float* W0, const float* W1, const float* W2, const float* W3,
    const float* Wf, const float* Wd, half_t* wt,
    half_t* Ain, half_t* Din){
  if (blockIdx.x < WTBLK2){
    // ---- weight transpose (feeds mlp only; no knn block reads wt) ----
    int idx = blockIdx.x * 1024 + threadIdx.x;
    if (idx >= WSZ) return;
    int base, nt, mode;            // mode: 0 plain(src), 1 W0, 2 W2, 3 Wd
    const float* src = W1;
    if (idx < 16384){ base = 0; nt = 8; mode = 1; }
    else if (idx < 32768){ base = 16384; nt = 8; mode = 0; src = W1; }
    else if (idx < 65536){ base = 32768; nt = 8; mode = 2; }
    else if (idx < 81920){ base = 65536; nt = 8; mode = 0; src = W3; }
    else if (idx < 98304){ base = 81920; nt = 8; mode = 0; src = Wf; }
    else { base = 98304; nt = 4; mode = 3; }
    int i = idx - base;
    int tile = i >> 9, e = i & 511;
    int lane = e >> 3, j = e & 7;
    int k0idx = tile / nt, tcol = tile - k0idx*nt;
    int n = tcol*16 + (lane & 15);
    int k = k0idx*32 + ((lane >> 4) << 3) + j;
    float val;
    if (mode == 0)      val = src[k*128 + n];
    else if (mode == 1) val = (k < 127) ? W0[k*128 + n] : 0.f;
    else if (mode == 2) val = (k == 127) ? 0.f
                             : ((k < 127) ? W2[k*128 + n] : W2[(k-1)*128 + n]);
    else                val = (k < 155) ? Wd[k*64 + n] : 0.f;
    wt[idx] = (half_t)val;
    return;
  }

  __shared__ float4 lp[N_C];         // 32 KB
  __shared__ int    sl[16*SLCAP];    // 8 KB
  int tid = threadIdx.x;
  int lane = tid & 63, wave = tid >> 6;
  const float* cc = codes + (size_t)indices[0] * N_C * CDIM;

  for (int c = tid; c < N_C; c += 1024) lp[c] = cpos4[c];
  __syncthreads();

  int q = (blockIdx.x - WTBLK2) * 16 + wave;
  float qx = qpts[q*3 + 0];
  float qy = qpts[q*3 + 1];
  float qz = qpts[q*3 + 2];
  float nqx = -2.0f*qx, nqy = -2.0f*qy, nqz = -2.0f*qz;
  float qq = fmaf(qx, qx, fmaf(qy, qy, qz*qz));   // |q|^2

  int cx = min((int)(qx * 16.0f), 15);
  int cy = min((int)(qy * 16.0f), 15);
  int cz = min((int)(qz * 16.0f), 15);
  int cell = cx | (cy << 4) | (cz << 8);
  int lox = min(max(cx - 4, 0), 7);
  int loy = min(max(cy - 4, 0), 7);
  int loz = min(max(cz - 4, 0), 7);
  int nl = cnt[cell];

  // One 16B load: this lane's 8 candidate indices.
  u16x8 cand8 = *(const u16x8*)(list + (size_t)cell * LSTORE + lane * 8);

  int p[NSLOT];
  int lanemin = KINF;
#pragma unroll
  for (int s = 0; s < NSLOT; s++){
    int j = lane*8 + s;
    int idx = (int)cand8[s] & 2047;   // mask stale pad -> safe LDS read
    float4 P = lp[idx];
    float sc = fmaf(P.x, nqx, fmaf(P.y, nqy, fmaf(P.z, nqz, P.w)));
    int pv = (__float_as_int(sc) & 0xFFFFF800) | idx;
    pv = (j < nl) ? pv : KINF;
    asm("" : "+v"(pv));
    p[s] = pv;
    lanemin = min(lanemin, pv);
  }

  // tau: truncated-exact threshold (>= 16 candidates pass, guaranteed).
  int tau = select16_tau(lanemin);

  int* slw = &sl[wave * SLCAP];
  int n = 0;
#pragma unroll
  for (int s = 0; s < NSLOT; s++){
    bool c = (p[s] <= tau);
    unsigned long long m = __ballot(c);
    if (m){
      if (n <= 64){
        if (c){
          int mb = mbcnt64(m);
          slw[n + mb] = p[s];
        }
      }
      n += (int)__popcll(m);
    }
  }
  __builtin_amdgcn_wave_barrier();

  int keep = KINF;
  bool need_fb = true;
  if (n >= KNN_K && n <= 64){
    int x = (lane < n) ? slw[lane] : KINF;
    int P2 = select16th(x);           // exact 16th smallest candidate
    unsigned long long wmask = __ballot(x <= P2);
    int pos = mbcnt64(wmask);
    if (x <= P2) slw[pos] = x;        // exactly 16 winners -> slots 0..15
    __builtin_amdgcn_wave_barrier();
    keep = (lane < KNN_K) ? slw[lane] : KINF;

    // Certificate: d^2 = s - 4 + |q|^2 (truncation < 2^-10) vs clearance^2.
    float d2u = __int_as_float(P2 & 0xFFFFF800) - 4.0f + qq + 0.002f;
    float lofx = lox * 0.0625f, lofy = loy * 0.0625f, lofz = loz * 0.0625f;
    float cl = 1e9f;
    if (lox > 0) cl = fminf(cl, qx - lofx);
    if (lox < 7) cl = fminf(cl, lofx + 0.5625f - qx);
    if (loy > 0) cl = fminf(cl, qy - lofy);
    if (loy < 7) cl = fminf(cl, lofy + 0.5625f - qy);
    if (loz > 0) cl = fminf(cl, qz - lofz);
    if (loz < 7) cl = fminf(cl, lofz + 0.5625f - qz);
    need_fb = !(d2u <= cl * cl);
  }
  if (need_fb) keep = knn_fallback(lp, nqx, nqy, nqz, lane);

  int ci = keep & 0x7FF;
  float4 P = lp[ci];
  float dx = qx - P.x, dy = qy - P.y, dz = qz - P.z;
  float d2 = fmaf(dz, dz, fmaf(dy, dy, dx*dx));
  float w = 1.0f / (d2 + 1e-16f);
  float wm = (lane < KNN_K) ? w : 0.0f;
  wm += dppxf(wm, 1);
  wm += dppxf(wm, 2);
  wm += __shfl_xor(wm, 4, 64);
  wm += dppxf(wm, 8);
  float wn = w / wm;

  // Winner table in LDS (broadcast reads) replaces 32 ds_bpermutes.
  if (lane < KNN_K){
    slw[64 + 2*lane]     = ci;
    slw[64 + 2*lane + 1] = __float_as_int(wn);
  }
  __builtin_amdgcn_wave_barrier();

  float acc = 0.f;
#pragma unroll
  for (int i = 0; i < KNN_K; i++){
    int   cb = slw[64 + 2*i];
    float wb = __int_as_float(slw[64 + 2*i + 1]);
    acc = fmaf(wb, cc[cb*CDIM + lane], acc);
  }
  size_t arow = (size_t)q * ASTRIDE;
  Ain[arow + lane] = (half_t)acc;

  float xv = (lane < 63) ? xyzdir[(size_t)q*90 + lane] : 0.f;
  Ain[arow + 64 + lane] = (half_t)xv;
  if (lane < 8) Ain[arow + 128 + lane] = (half_t)0.f;
  if (lane < 40){
    float dv = (lane < 27) ? xyzdir[(size_t)q*90 + 63 + lane] : 0.f;
    Din[(size_t)q*DSTRIDE + lane] = (half_t)dv;
  }
}

// ---------------------------------------------------------------------------
// Kernel 2: fused MFMA MLP, 64 queries/block — R2 known-good version, frozen.
// ---------------------------------------------------------------------------
template<int NCH, int NT>
__device__ inline void mfma_pl(const half_t* act, int astride, int rowbase,
                               const half_t* wlayer, int nt, int ktbase,
                               int tcolbase, v4f acc[2][NT], int lane){
  v8h breg[NCH*NT];
#pragma unroll
  for (int c = 0; c < NCH; c++){
#pragma unroll
    for (int t = 0; t < NT; t++){
      const half_t* bp = wlayer +
          ((size_t)(((ktbase + c)*nt + tcolbase + t) << 9) + (lane << 3));
      breg[c*NT + t] = *(const v8h*)bp;
    }
  }
  int m = lane & 15, quad = lane >> 4;
#pragma unroll
  for (int c = 0; c < NCH; c++){
    v8h a0 = *(const v8h*)&act[(rowbase + m)*astride + c*32 + quad*8];
    v8h a1 = *(const v8h*)&act[(rowbase + 16 + m)*astride + c*32 + quad*8];
#pragma unroll
    for (int t = 0; t < NT; t++){
      acc[0][t] = __builtin_amdgcn_mfma_f32_16x16x32_f16(a0, breg[c*NT + t], acc[0][t], 0, 0, 0);
      acc[1][t] = __builtin_amdgcn_mfma_f32_16x16x32_f16(a1, breg[c*NT + t], acc[1][t], 0, 0, 0);
    }
  }
}

template<int NT>
__device__ inline void epilogue64(v4f acc[2][NT], half_t* outb, int rowbase,
                                  int colbase, const float* bias, bool relu,
                                  int lane){
  int n = lane & 15, quad = lane >> 4;
#pragma unroll
  for (int t = 0; t < NT; t++){
    int col = colbase + t*16 + n;
    float bv = bias[col];
#pragma unroll
    for (int g = 0; g < 2; g++){
#pragma unroll
      for (int r = 0; r < 4; r++){
        float v = acc[g][t][r] + bv;
        if (relu) v = fmaxf(v, 0.f);
        outb[(rowbase + g*16 + quad*4 + r)*ASTRIDE + col] = (half_t)v;
      }
    }
  }
}

__global__ __launch_bounds__(512, 6) void mlp_mfma(
    const half_t* Ain, const half_t* Din, const half_t* wt,
    const float* b0, const float* b1, const float* b2, const float* b3,
    const float* bfb, const float* bdb,
    const float* Wsb, const float* bsb, const float* Wrb, const float* brb,
    float* out){
  __shared__ __align__(16) half_t Abuf[64*ASTRIDE];
  __shared__ __align__(16) half_t Pbuf[64*ASTRIDE];
  __shared__ __align__(16) half_t Qbuf[64*ASTRIDE];

  int tid = threadIdx.x, lane = tid & 63, wave = tid >> 6;
  int qbase = blockIdx.x * 64;

  for (int i = tid; i < 64*17; i += 512){
    int r = i / 17, c8 = i - r*17;
    *(uint4*)&Abuf[r*ASTRIDE + (c8 << 3)] =
        *(const uint4*)&Ain[(size_t)(qbase + r)*ASTRIDE + (c8 << 3)];
  }
  __syncthreads();

  int rowbase  = (wave >> 2) * 32;
  int colq     = wave & 3;
  int colbase  = colq * 32;
  int tcolbase = colq * 2;
  v4f acc[2][2];
  v4f accd[2][1];

  const half_t* wt0 = wt;
  const half_t* wt1 = wt + 16384;
  const half_t* wt2 = wt + 32768;
  const half_t* wt3 = wt + 65536;
  const half_t* wtf = wt + 81920;
  const half_t* wtd = wt + 98304;

#define ZACC22() { for (int g_ = 0; g_ < 2; g_++) for (int t_ = 0; t_ < 2; t_++) \
                   for (int e_ = 0; e_ < 4; e_++) acc[g_][t_][e_] = 0.f; }

  // L0: A @ W0 -> P (relu)
  ZACC22();
  mfma_pl<4,2>(Abuf, ASTRIDE, rowbase, wt0, 8, 0, tcolbase, acc, lane);
  epilogue64<2>(acc, Pbuf, rowbase, colbase, b0, true, lane);
  __syncthreads();

  // L1: P @ W1 -> Q (relu)
  ZACC22();
  mfma_pl<4,2>(Pbuf, ASTRIDE, rowbase, wt1, 8, 0, tcolbase, acc, lane);
  epilogue64<2>(acc, Qbuf, rowbase, colbase, b1, true, lane);
  __syncthreads();

  // L2: [input_xyz | h1] @ W2 -> P (relu)   (K = 256)
  ZACC22();
  mfma_pl<4,2>(Abuf, ASTRIDE, rowbase, wt2, 8, 0, tcolbase, acc, lane);
  mfma_pl<4,2>(Qbuf, ASTRIDE, rowbase, wt2, 8, 4, tcolbase, acc, lane);
  epilogue64<2>(acc, Pbuf, rowbase, colbase, b2, true, lane);
  __syncthreads();

  // L3: P @ W3 -> A (h3, kept for sigma; input_xyz dead)
  ZACC22();
  mfma_pl<4,2>(Pbuf, ASTRIDE, rowbase, wt3, 8, 0, tcolbase, acc, lane);
  epilogue64<2>(acc, Abuf, rowbase, colbase, b3, true, lane);
  __syncthreads();

  // Wf: A(h3) @ Wf -> P (no relu)
  ZACC22();
  mfma_pl<4,2>(Abuf, ASTRIDE, rowbase, wtf, 8, 0, tcolbase, acc, lane);
  epilogue64<2>(acc, Pbuf, rowbase, colbase, bfb, false, lane);
  __syncthreads();

  // Wd: [P(final) | Din(dir, straight from global/L2)] @ Wd -> Q[:,0:64]
#pragma unroll
  for (int g_ = 0; g_ < 2; g_++)
#pragma unroll
    for (int e_ = 0; e_ < 4; e_++) accd[g_][0][e_] = 0.f;
  mfma_pl<4,1>(Pbuf, ASTRIDE, rowbase, wtd, 4, 0, colq, accd, lane);
  mfma_pl<1,1>(Din + (size_t)qbase*DSTRIDE, DSTRIDE, rowbase, wtd, 4, 4, colq,
               accd, lane);
  epilogue64<1>(accd, Qbuf, rowbase, colq * 16, bdb, true, lane);
  __syncthreads();

  // Tail: sigma = h3(Abuf).Ws + bs ; rgb = d(Qbuf).Wr + br  (8 thr/query)
  {
    int q = tid >> 3, part = tid & 7;
    float s = 0.f;
#pragma unroll
    for (int k = 0; k < 16; k++){
      int kk = part*16 + k;
      s = fmaf((float)Abuf[q*ASTRIDE + kk], Wsb[kk], s);
    }
    s += __shfl_xor(s, 1, 64); s += __shfl_xor(s, 2, 64); s += __shfl_xor(s, 4, 64);

    float r3[3];
#pragma unroll
    for (int c2 = 0; c2 < 3; c2++){
      float rv = 0.f;
#pragma unroll
      for (int k = 0; k < 8; k++){
        int kk = part*8 + k;
        rv = fmaf((float)Qbuf[q*ASTRIDE + kk], Wrb[kk*3 + c2], rv);
      }
      rv += __shfl_xor(rv, 1, 64); rv += __shfl_xor(rv, 2, 64); rv += __shfl_xor(rv, 4, 64);
      r3[c2] = rv;
    }
    if (part == 0){
      size_t ob = ((size_t)(qbase + q)) * 4;
      out[ob + 0] = r3[0] + brb[0];
      out[ob + 1] = r3[1] + brb[1];
      out[ob + 2] = r3[2] + brb[2];
      out[ob + 3] = s + bsb[0];
    }
  }
}

// ---------------------------------------------------------------------------
extern "C" void kernel_launch(void* const* d_in, const int* in_sizes, int n_in,
                              void* d_out, int out_size, void* d_ws, size_t ws_size,
                              hipStream_t stream){
  (void)in_sizes; (void)n_in; (void)out_size; (void)ws_size;

  const int*   indices = (const int*)d_in[0];
  const float* qpts    = (const float*)d_in[1];
  const float* xyzdir  = (const float*)d_in[2];
  const float* cpos    = (const float*)d_in[3];
  const float* codes   = (const float*)d_in[4];
  const float* W0 = (const float*)d_in[5];
  const float* b0 = (const float*)d_in[6];
  const float* W1 = (const float*)d_in[7];
  const float* b1 = (const float*)d_in[8];
  const float* W2 = (const float*)d_in[9];
  const float* b2 = (const float*)d_in[10];
  const float* W3 = (const float*)d_in[11];
  const float* b3 = (const float*)d_in[12];
  const float* Wf = (const float*)d_in[13];
  const float* bf = (const float*)d_in[14];
  const float* Wd = (const float*)d_in[15];
  const float* bd = (const float*)d_in[16];
  const float* Ws = (const float*)d_in[17];
  const float* bs = (const float*)d_in[18];
  const float* Wr = (const float*)d_in[19];
  const float* br = (const float*)d_in[20];

  // ws layout (16-B aligned): Ain | Din | wt | cpos4 | list | cnt
  half_t* Ain            = (half_t*)d_ws;                          // 17,825,792
  half_t* Din            = (half_t*)((char*)d_ws + 17825792);      //  5,242,880
  half_t* wt             = (half_t*)((char*)d_ws + 23068672);      //    217,088
  float4* cpos4          = (float4*)((char*)d_ws + 23285760);      //     32,768
  unsigned short* list   = (unsigned short*)((char*)d_ws + 23318528); // 4,194,304
  int* cnt               = (int*)((char*)d_ws + 27512832);         //     16,384

  // prep: grid lists (128 blocks) + cpos4 (4 blocks)
  prep_kernel<<<GCELLS/8 + 4, 512, 0, stream>>>(indices, cpos,
                                                cpos4, list, cnt);
  // knn launch: 106 wtrans blocks (overlap) + 4096 query blocks (1024 thr)
  knn_kernel<<<WTBLK2 + KNNBLK, 1024, 0, stream>>>(indices, qpts, cpos4, list,
                                                   cnt, codes, xyzdir,
                                                   W0, W1, W2, W3, Wf, Wd, wt,
                                                   Ain, Din);
  mlp_mfma<<<N_Q/64, 512, 0, stream>>>(Ain, Din, wt,
                                       b0, b1, b2, b3, bf, bd, Ws, bs, Wr, br,
                                       (float*)d_out);
}